// Round 12
// baseline (166.160 us; speedup 1.0000x reference)
//
#include <hip/hip_runtime.h>

using f16   = _Float16;
using f16x4 = __attribute__((ext_vector_type(4))) _Float16;
using f16x8 = __attribute__((ext_vector_type(8))) _Float16;
using f32x4 = __attribute__((ext_vector_type(4))) float;
using u32x4 = __attribute__((ext_vector_type(4))) unsigned int;
using fp16x2_raw = __fp16 __attribute__((ext_vector_type(2)));

#define MFMA16(a, b, c) __builtin_amdgcn_mfma_f32_16x16x32_f16((a), (b), (c), 0, 0, 0)

namespace {
constexpr int kT = 8, kWd = 14, kS = 196;
constexpr int kN = 1568;      // T*S (sequence length per batch)
constexpr int kM = 3136;      // B*N (GEMM rows)
constexpr int kHeads = 12;
constexpr int kNp = 1664;     // padded N (13*128)
constexpr float kLog2e = 1.4426950408889634f;
// workspace byte offsets (all 256-aligned); total 25378816 (proven budget)
constexpr size_t OFF_Q    = 4718592;      // qf   [24][Np][64] f16 (q*log2e); REUSED as O
constexpr size_t OFF_KF   = 14942208;     // kfrag[24][13][8][2][64][8] f16 (key-permuted)
constexpr size_t OFF_KONE = 20054016;     // konefrag [13][8][2][64][8] f16 (key-permuted)
constexpr size_t OFF_VSWZ = 20267008;     // vswz [24][13][4][4][64][8] f16
constexpr size_t WS_TOTAL = 25378816;
constexpr int kKoneTot = 13 * 8 * 2 * 64 * 8;   // 106496 f16 elements

__device__ inline f16x4 pack4(float4 v) {
  union { fp16x2_raw h2[2]; f16x4 f4; } u;
  u.h2[0] = __builtin_amdgcn_cvt_pkrtz(v.x, v.y);
  u.h2[1] = __builtin_amdgcn_cvt_pkrtz(v.z, v.w);
  return u.f4;
}

__device__ inline float fast_exp2(float x) {
#if __has_builtin(__builtin_amdgcn_exp2f)
  return __builtin_amdgcn_exp2f(x);
#else
  return __expf(x * 0.6931471805599453f);
#endif
}

// async global -> LDS DMA, 16 bytes per lane (zero VGPR round-trip)
__device__ inline void gload_lds16(const f16* g, f16* l) {
  __builtin_amdgcn_global_load_lds(
      (const __attribute__((address_space(1))) unsigned int*)g,
      (__attribute__((address_space(3))) unsigned int*)l,
      16, 0, 0);
}

// dot of 64-dim q (registers, f16) with 64-dim R row (LDS, f16)
__device__ inline float dotqLDS(const f16x8* qh, const f16* Rrow) {
  float s = 0.f;
#pragma unroll
  for (int i = 0; i < 8; ++i) {
    f16x8 a = qh[i];
    f16x8 b = *(const f16x8*)(Rrow + i * 8);
#pragma unroll
    for (int k = 0; k < 8; ++k) s += (float)a[k] * (float)b[k];
  }
  return s;
}
}

// ---------------- QKV GEMM: 128x128, fp32 in-staging conversion ----------------
// + fused konefrag generation (one element per thread, independent writes;
//   consumed by arp_attn one launch later).
// + XCD-bijective block swizzle (450 = 2x57 + 6x56): blocks sharing an A-panel
//   (same m0) land on one XCD's L2.
__global__ __launch_bounds__(256, 2) void arp_gemm_qkv(
    const float* __restrict__ X, const float* __restrict__ qkvw,
    f16* __restrict__ qf, f16* __restrict__ kfrag, f16* __restrict__ vswz,
    f16* __restrict__ konefrag) {
  __shared__ char smem[34816];
  f16* sA = (f16*)smem;               // [128][40]
  f16* sB = (f16*)(smem + 10240);     // [128][40]
  f16* sE = (f16*)smem;               // [128][136] (epilogue)
  const int tid = threadIdx.x, lane = tid & 63, wv = tid >> 6;

  // ---- fused konefrag generation (key-permuted one-hot ext fragments) ----
  {
    int g = (blockIdx.y * 18 + blockIdx.x) * 256 + tid;
    if (g < kKoneTot) {
      int j = g & 7;
      int ln = (g >> 3) & 63;
      int s2 = (g >> 9) & 1;
      int nt = (g >> 10) & 7;
      int kt = g >> 13;
      int slot = ln & 15, qd = ln >> 4;
      int kin = (nt >> 1) * 32 + (slot >> 2) * 8 + (nt & 1) * 4 + (slot & 3);
      int key = kt * 128 + kin;
      int c = s2 * 32 + qd * 8 + j;
      int t2 = key / kS; int rm = key - t2 * kS;
      int h2 = rm / kWd; int w2 = rm - h2 * kWd;
      if (t2 > kT - 1) t2 = kT - 1;
      float v = 0.f;
      if (c == h2) v = 1.f;
      else if (c == 14 + w2) v = 1.f;
      else if (c == 28 + t2) v = 1.f;
      else if (c == 36 && key >= kN) v = 1.f;
      konefrag[g] = (f16)v;
    }
  }

  // ---- XCD-bijective swizzle: 450 blocks, q=56, r=2 ----
  int orig = blockIdx.y * 18 + blockIdx.x;
  int xcd = orig & 7;
  int base = (xcd < 2) ? xcd * 57 : 2 * 57 + (xcd - 2) * 56;
  int wgid = base + (orig >> 3);
  const int m0 = (wgid / 18) * 128, n0 = (wgid % 18) * 128;

  const int wm = (wv & 1) * 64, wn = (wv >> 1) * 64;
  const int frow = lane & 15, quad = lane >> 4, fcol = quad * 8;
  const f32x4 vzero = {0.f, 0.f, 0.f, 0.f};
  f32x4 acc[4][4];
#pragma unroll
  for (int i = 0; i < 4; ++i)
#pragma unroll
    for (int j = 0; j < 4; ++j) acc[i][j] = vzero;

  float4 pA[2][2], pB[2][2];
#pragma unroll
  for (int i = 0; i < 2; ++i) {
    int idx = i * 256 + tid;
    int r = idx >> 2, c8 = (idx & 3) * 8;
    int gm = m0 + r; if (gm >= kM) gm = kM - 1;
    pA[i][0] = *(const float4*)(X + (size_t)gm * 768 + c8);
    pA[i][1] = *(const float4*)(X + (size_t)gm * 768 + c8 + 4);
    pB[i][0] = *(const float4*)(qkvw + (size_t)(n0 + r) * 768 + c8);
    pB[i][1] = *(const float4*)(qkvw + (size_t)(n0 + r) * 768 + c8 + 4);
  }

  for (int kt = 0; kt < 24; ++kt) {
#pragma unroll
    for (int i = 0; i < 2; ++i) {
      int idx = i * 256 + tid;
      int r = idx >> 2, c8 = (idx & 3) * 8;
      union { f16x4 h[2]; u32x4 u; } ua, ub;
      ua.h[0] = pack4(pA[i][0]); ua.h[1] = pack4(pA[i][1]);
      ub.h[0] = pack4(pB[i][0]); ub.h[1] = pack4(pB[i][1]);
      *(u32x4*)&sA[r * 40 + c8] = ua.u;
      *(u32x4*)&sB[r * 40 + c8] = ub.u;
    }
    __syncthreads();
    if (kt < 23) {
      int ko = (kt + 1) * 32;
#pragma unroll
      for (int i = 0; i < 2; ++i) {
        int idx = i * 256 + tid;
        int r = idx >> 2, c8 = (idx & 3) * 8;
        int gm = m0 + r; if (gm >= kM) gm = kM - 1;
        pA[i][0] = *(const float4*)(X + (size_t)gm * 768 + ko + c8);
        pA[i][1] = *(const float4*)(X + (size_t)gm * 768 + ko + c8 + 4);
        pB[i][0] = *(const float4*)(qkvw + (size_t)(n0 + r) * 768 + ko + c8);
        pB[i][1] = *(const float4*)(qkvw + (size_t)(n0 + r) * 768 + ko + c8 + 4);
      }
    }
    f16x8 af[4], bf[4];
#pragma unroll
    for (int t = 0; t < 4; ++t) {
      af[t] = *(const f16x8*)&sA[(wm + t * 16 + frow) * 40 + fcol];
      bf[t] = *(const f16x8*)&sB[(wn + t * 16 + frow) * 40 + fcol];
    }
#pragma unroll
    for (int mt = 0; mt < 4; ++mt)
#pragma unroll
      for (int nt = 0; nt < 4; ++nt)
        acc[mt][nt] = MFMA16(af[mt], bf[nt], acc[mt][nt]);
    __syncthreads();
  }

  const int which = n0 / 768;   // 0=q, 1=k, 2=v
  if (which == 2) {
#pragma unroll
    for (int mt = 0; mt < 4; ++mt)
#pragma unroll
      for (int nt = 0; nt < 4; ++nt) {
        int cl = wn + nt * 16 + frow;
#pragma unroll
        for (int rg = 0; rg < 4; ++rg) {
          int rl = wm + mt * 16 + quad * 4 + rg;
          sE[cl * 136 + rl] = (f16)acc[mt][nt][rg];
        }
      }
    __syncthreads();
    int cl = tid >> 1;
    int rb = (tid & 1) * 64;
    int rem = n0 + cl - 1536;
    int hh = rem >> 6, d = rem & 63;
    int td = d >> 4, fr = d & 15;
#pragma unroll
    for (int j = 0; j < 8; ++j) {
      int ms = m0 + rb + j * 8;
      if (ms < kM) {
        int bb2 = (ms >= kN) ? 1 : 0;
        int ns = ms - bb2 * kN;
        int bh = bb2 * kHeads + hh;
        int kt2 = ns >> 7, kr = ns & 127;
        int kc = kr >> 5, qd = (kr >> 3) & 3;
        f16* dst = vswz + ((((size_t)(bh * 13 + kt2)) * 4 + td) * 4 + kc) * 512
                        + (qd * 16 + fr) * 8;
        *(u32x4*)dst = *(const u32x4*)&sE[cl * 136 + rb + j * 8];
      }
    }
  } else {
#pragma unroll
    for (int mt = 0; mt < 4; ++mt) {
      int rbase = m0 + wm + mt * 16 + quad * 4;
#pragma unroll
      for (int nt = 0; nt < 4; ++nt) {
        int col0 = n0 + wn + nt * 16;
        int rem = col0 - which * 768;
        int hh = rem >> 6;
        int d = (rem & 63) + frow;
        int s = d >> 5, qd2 = (d >> 3) & 3, j = d & 7;
#pragma unroll
        for (int rg = 0; rg < 4; ++rg) {
          int m = rbase + rg;
          if (m < kM) {
            int bb2 = (m >= kN) ? 1 : 0;
            int ns = m - bb2 * kN;
            int bh = bb2 * kHeads + hh;
            float av = acc[mt][nt][rg];
            if (which == 0) {
              av *= kLog2e;
              qf[((size_t)bh * kNp + ns) * 64 + d] = (f16)av;
            } else {
              av *= 0.125f;
              // key-permuted storage: swapped-QK output becomes PV-ready
              int kt2 = ns >> 7;
              int kin = ns & 127;
              int nt2 = ((kin >> 5) << 1) | ((kin >> 2) & 1);
              int slot = ((kin >> 3) & 3) * 4 + (kin & 3);
              kfrag[(((size_t)(bh * 13 + kt2) * 8 + nt2) * 2 + s) * 512
                    + (qd2 * 16 + slot) * 8 + j] = (f16)av;
            }
          }
        }
      }
    }
  }
}

// ---------------- flash attention; swapped QK^T, dbuf half-tile K-loop ---------
// 26 half-tiles (64 keys each), two 24KB LDS buffers {Ka|Kb|V}. ONE barrier per
// iteration: loop-top __syncthreads drains the DMA issued last iteration into
// cur (alt's readers finished last iteration), then next-tile DMA is issued
// into alt IMMEDIATELY so its latency overlaps the whole compute body.
// Arithmetic order identical to the 13x128 version (bitwise-same results).
__global__ __launch_bounds__(256, 3) void arp_attn(
    const f16* qf,
    const float* __restrict__ Rh, const float* __restrict__ Rw, const float* __restrict__ Rt,
    const f16* __restrict__ kfrag, const f16* __restrict__ konefrag,
    const f16* __restrict__ vswz, f16* qfO) {
  __shared__ char pool[49152];
  // buffer b at pool + b*24576: Ka [4nt][2s][64][8] | Kb same | V [4td][2kc][64][8]
  f16* sQE = (f16*)pool;             // 8192 B: [64][64] qe staging (prologue only)
  f16* sR  = (f16*)(pool + 8192);    // 9936 B: 69 rows x 72 f16 (prologue only)

  const int tid = threadIdx.x, lane = tid & 63, wv = tid >> 6;
  // XCD swizzle (bijective, 600 = 8*75): each XCD owns 75 consecutive work items
  const int Lb  = blockIdx.y * 25 + blockIdx.x;
  const int Lw  = (Lb & 7) * 75 + (Lb >> 3);
  const int q0 = (Lw % 25) * 64;
  const int bh = Lw / 25;
  const int frow = lane & 15, quad = lane >> 4;
  const f32x4 vzero = {0.f, 0.f, 0.f, 0.f};

  const f16* kba = kfrag + (size_t)bh * 13 * 8192;
  const f16* vba = vswz + (size_t)bh * 13 * 8192;

  // ---- stage R tables: rows 0..26 = Rh, 27..53 = Rw, 54..68 = Rt ----
  for (int g = tid; g < 69 * 16; g += 256) {
    int row = g >> 4, c4 = (g & 15) * 4;
    const float* src = (row < 27) ? Rh + row * 64 + c4
                     : (row < 54) ? Rw + (row - 27) * 64 + c4
                                  : Rt + (row - 54) * 64 + c4;
    *(f16x4*)&sR[row * 72 + c4] = pack4(*(const float4*)src);
  }
  __syncthreads();

  // ---- fused qext, wave-specialized, dots from LDS ----
  {
    int q = q0 + lane;
    int qc = (q < kN) ? q : kN - 1;    // clamp so table indices stay in range
    int tq = qc / kS, sr = qc - tq * kS;
    int hq = sr / kWd, wq = sr - hq * kWd;
    if (wv < 3) {
      f16x8 qh[8];
      const f16x8* qv8 = (const f16x8*)(qf + ((size_t)bh * kNp + q) * 64);
#pragma unroll
      for (int i = 0; i < 8; ++i) qh[i] = qv8[i];
      if (wv == 0) {
#pragma unroll
        for (int e = 0; e < 14; ++e)
          sQE[lane * 64 + e] = (f16)dotqLDS(qh, &sR[(hq - e + 13) * 72]);
      } else if (wv == 1) {
#pragma unroll
        for (int e = 0; e < 14; ++e)
          sQE[lane * 64 + 14 + e] = (f16)dotqLDS(qh, &sR[(wq - e + 40) * 72]);
      } else {
#pragma unroll
        for (int e = 0; e < 8; ++e)
          sQE[lane * 64 + 28 + e] = (f16)dotqLDS(qh, &sR[(tq - e + 61) * 72]);
      }
    } else {
      sQE[lane * 64 + 36] = (f16)(-30000.f);
#pragma unroll
      for (int e = 37; e < 64; ++e) sQE[lane * 64 + e] = (f16)0.f;
    }
  }
  __syncthreads();

  f16x8 aQ0, aQ1, aQE0, aQE1;
  {
    int row = q0 + wv * 16 + frow;
    const f16* qp = qf + ((size_t)bh * kNp + row) * 64;
    aQ0 = *(const f16x8*)(qp + quad * 8);
    aQ1 = *(const f16x8*)(qp + 32 + quad * 8);
    int rl = wv * 16 + frow;
    aQE0 = *(const f16x8*)&sQE[rl * 64 + quad * 8];
    aQE1 = *(const f16x8*)&sQE[rl * 64 + 32 + quad * 8];
  }
  __syncthreads();   // all sQE/sR reads complete before DMA clobbers buf0

  // ---- issue half-tile 0 staging into buf0 (drained at first loop barrier) ----
  {
    f16* dst = (f16*)pool;
#pragma unroll
    for (int i = 0; i < 6; ++i) {
      int u = i * 256 + tid;
      const f16* src;
      if (u < 512)       src = kba + u * 8;
      else if (u < 1024) src = konefrag + (u - 512) * 8;
      else {
        int v2 = u - 1024;
        src = vba + (v2 >> 7) * 2048 + (v2 & 127) * 8;
      }
      gload_lds16(src, dst + u * 8);
    }
  }

  float den = 0.f;
  f32x4 Oc[4];
#pragma unroll
  for (int t = 0; t < 4; ++t) Oc[t] = vzero;

  for (int ht = 0; ht < 26; ++ht) {
    __syncthreads();  // drains DMA into cur; alt's readers finished last iter

    if (ht < 25) {    // issue next half-tile into alt; overlaps whole body
      int h1 = (ht + 1) & 1;
      const f16* kfa = kba + (size_t)((ht + 1) >> 1) * 8192 + h1 * 4096;
      const f16* koa = konefrag + (size_t)((ht + 1) >> 1) * 8192 + h1 * 4096;
      const f16* vfa = vba + (size_t)((ht + 1) >> 1) * 8192;
      f16* dst = (f16*)(pool + h1 * 24576);
#pragma unroll
      for (int i = 0; i < 6; ++i) {
        int u = i * 256 + tid;
        const f16* src;
        if (u < 512)       src = kfa + u * 8;
        else if (u < 1024) src = koa + (u - 512) * 8;
        else {
          int v2 = u - 1024;
          src = vfa + (v2 >> 7) * 2048 + h1 * 1024 + (v2 & 127) * 8;
        }
        gload_lds16(src, dst + u * 8);
      }
    }

    const f16* bKa = (const f16*)(pool + (ht & 1) * 24576);
    const f16* bKb = bKa + 4096;
    const f16* bVv = bKa + 8192;

    f32x4 Sc[4];
    __builtin_amdgcn_s_setprio(1);
#pragma unroll
    for (int ntl = 0; ntl < 4; ++ntl) {
      const f16* ka = &bKa[ntl * 1024 + lane * 8];
      const f16* kb = &bKb[ntl * 1024 + lane * 8];
      f32x4 s = MFMA16(*(const f16x8*)(ka), aQ0, vzero);
      s = MFMA16(*(const f16x8*)(ka + 512), aQ1, s);
      s = MFMA16(*(const f16x8*)(kb), aQE0, s);
      Sc[ntl] = MFMA16(*(const f16x8*)(kb + 512), aQE1, s);
    }
    __builtin_amdgcn_s_setprio(0);
    f16x8 bV[4][2];
#pragma unroll
    for (int td = 0; td < 4; ++td)
#pragma unroll
      for (int kcl = 0; kcl < 2; ++kcl)
        bV[td][kcl] = *(const f16x8*)&bVv[(td * 2 + kcl) * 512 + lane * 8];

#pragma unroll
    for (int ntl = 0; ntl < 4; ++ntl)
#pragma unroll
      for (int r = 0; r < 4; ++r)
        Sc[ntl][r] = fast_exp2(Sc[ntl][r]);

    __builtin_amdgcn_s_setprio(1);
#pragma unroll
    for (int kcl = 0; kcl < 2; ++kcl) {
      union { _Float16 h[8]; f16x8 v; } up;
#pragma unroll
      for (int r = 0; r < 4; ++r) {
        up.h[r]     = (f16)Sc[2 * kcl][r];
        up.h[4 + r] = (f16)Sc[2 * kcl + 1][r];
      }
#pragma unroll
      for (int r = 0; r < 4; ++r)
        den += (float)up.h[r] + (float)up.h[4 + r];
#pragma unroll
      for (int td = 0; td < 4; ++td)
        Oc[td] = MFMA16(up.v, bV[td][kcl], Oc[td]);
    }
    __builtin_amdgcn_s_setprio(0);
  }

  // denominator: per-lane partial covers quad-owned keys; reduce across quads
  den += __shfl_xor(den, 16, 64);
  den += __shfl_xor(den, 32, 64);
  float lr[4];
#pragma unroll
  for (int r = 0; r < 4; ++r)
    lr[r] = 1.f / __shfl(den, quad * 4 + r, 64);
#pragma unroll
  for (int td = 0; td < 4; ++td)
#pragma unroll
    for (int r = 0; r < 4; ++r) {
      int row = q0 + wv * 16 + quad * 4 + r;
      if (row < kN) {
        float val = Oc[td][r] * lr[r];
        qfO[((size_t)bh * kNp + row) * 64 + td * 16 + frow] = (f16)val;
      }
    }
}

// ---------------- proj GEMM: 64x64 tiles (grid 588) + XCD-bijective swizzle ----
__global__ __launch_bounds__(256, 4) void arp_gemm_proj(
    const f16* A, const float* __restrict__ projw,
    const float* __restrict__ bias, float* __restrict__ out) {
  __shared__ f16 sA[64 * 40];     // 5120 B
  __shared__ f16 sB[64 * 40];     // 5120 B
  const int tid = threadIdx.x, lane = tid & 63, wv = tid >> 6;

  // XCD-bijective swizzle: 588 blocks, q=73, r=4
  int orig = blockIdx.y * 12 + blockIdx.x;
  int xcd = orig & 7;
  int base = (xcd < 4) ? xcd * 74 : 4 * 74 + (xcd - 4) * 73;
  int wgid = base + (orig >> 3);
  const int m0 = (wgid / 12) * 64, n0 = (wgid % 12) * 64;

  const int frow = lane & 15, quad = lane >> 4, fcol = quad * 8;
  const f32x4 vzero = {0.f, 0.f, 0.f, 0.f};
  f32x4 acc[4];
#pragma unroll
  for (int j = 0; j < 4; ++j) acc[j] = vzero;

  u32x4 pA;
  float4 pB[2];
  {
    int r = tid >> 2, c8 = (tid & 3) * 8;
    int m = m0 + r;
    int bb = (m >= kN) ? 1 : 0;
    int ns = m - bb * kN;
    pA = *(const u32x4*)(A + ((size_t)(bb * kHeads) * kNp + ns) * 64 + c8);
    pB[0] = *(const float4*)(projw + (size_t)(n0 + r) * 768 + c8);
    pB[1] = *(const float4*)(projw + (size_t)(n0 + r) * 768 + c8 + 4);
  }

  for (int kt = 0; kt < 24; ++kt) {
    {
      int r = tid >> 2, c8 = (tid & 3) * 8;
      *(u32x4*)&sA[r * 40 + c8] = pA;
      union { f16x4 h[2]; u32x4 u; } ub;
      ub.h[0] = pack4(pB[0]); ub.h[1] = pack4(pB[1]);
      *(u32x4*)&sB[r * 40 + c8] = ub.u;
    }
    __syncthreads();
    if (kt < 23) {
      int k1 = kt + 1;
      int hd = k1 >> 1, dof = (k1 & 1) * 32;
      int r = tid >> 2, c8 = (tid & 3) * 8;
      int m = m0 + r;
      int bb = (m >= kN) ? 1 : 0;
      int ns = m - bb * kN;
      pA = *(const u32x4*)(A + ((size_t)(bb * kHeads + hd) * kNp + ns) * 64 + dof + c8);
      pB[0] = *(const float4*)(projw + (size_t)(n0 + r) * 768 + k1 * 32 + c8);
      pB[1] = *(const float4*)(projw + (size_t)(n0 + r) * 768 + k1 * 32 + c8 + 4);
    }
    f16x8 af = *(const f16x8*)&sA[(wv * 16 + frow) * 40 + fcol];
    f16x8 bf[4];
#pragma unroll
    for (int u = 0; u < 4; ++u)
      bf[u] = *(const f16x8*)&sB[(u * 16 + frow) * 40 + fcol];
#pragma unroll
    for (int u = 0; u < 4; ++u)
      acc[u] = MFMA16(af, bf[u], acc[u]);
    __syncthreads();
  }
#pragma unroll
  for (int u = 0; u < 4; ++u) {
    int col = n0 + u * 16 + frow;
    float bv = bias[col];
#pragma unroll
    for (int rg = 0; rg < 4; ++rg) {
      int m = m0 + wv * 16 + quad * 4 + rg;
      out[(size_t)m * 768 + col] = acc[u][rg] + bv;
    }
  }
}

extern "C" void kernel_launch(void* const* d_in, const int* in_sizes, int n_in,
                              void* d_out, int out_size, void* d_ws, size_t ws_size,
                              hipStream_t stream) {
  if (ws_size < WS_TOTAL) return;
  const float* x      = (const float*)d_in[0];
  const float* qkv_w  = (const float*)d_in[1];
  const float* proj_w = (const float*)d_in[2];
  const float* proj_b = (const float*)d_in[3];
  const float* rph    = (const float*)d_in[4];
  const float* rpw    = (const float*)d_in[5];
  const float* rpt    = (const float*)d_in[6];
  char* ws = (char*)d_ws;
  f16* qf       = (f16*)(ws + OFF_Q);     // becomes O after attn (in-place)
  f16* kfrag    = (f16*)(ws + OFF_KF);
  f16* konefrag = (f16*)(ws + OFF_KONE);
  f16* vswz     = (f16*)(ws + OFF_VSWZ);

  arp_gemm_qkv<<<dim3(18, 25), 256, 0, stream>>>(x, qkv_w, qf, kfrag, vswz, konefrag);
  arp_attn<<<dim3(25, 24), 256, 0, stream>>>(qf, rph, rpw, rpt, kfrag, konefrag, vswz, qf);
  arp_gemm_proj<<<dim3(12, 49), 256, 0, stream>>>(qf, proj_w, proj_b, (float*)d_out);
}

// Round 13
// 160.724 us; speedup vs baseline: 1.0338x; 1.0338x over previous
//
#include <hip/hip_runtime.h>

using f16   = _Float16;
using f16x4 = __attribute__((ext_vector_type(4))) _Float16;
using f16x8 = __attribute__((ext_vector_type(8))) _Float16;
using f32x4 = __attribute__((ext_vector_type(4))) float;
using u32x4 = __attribute__((ext_vector_type(4))) unsigned int;
using fp16x2_raw = __fp16 __attribute__((ext_vector_type(2)));

#define MFMA16(a, b, c) __builtin_amdgcn_mfma_f32_16x16x32_f16((a), (b), (c), 0, 0, 0)

namespace {
constexpr int kT = 8, kWd = 14, kS = 196;
constexpr int kN = 1568;      // T*S (sequence length per batch)
constexpr int kM = 3136;      // B*N (GEMM rows)
constexpr int kHeads = 12;
constexpr int kNp = 1664;     // padded N (13*128)
constexpr float kLog2e = 1.4426950408889634f;
// workspace byte offsets (all 256-aligned); total 25378816 (proven budget)
constexpr size_t OFF_Q    = 4718592;      // qf   [24][Np][64] f16 (q*log2e); REUSED as O
constexpr size_t OFF_KF   = 14942208;     // kfrag[24][13][8][2][64][8] f16 (key-permuted)
constexpr size_t OFF_KONE = 20054016;     // konefrag [13][8][2][64][8] f16 (key-permuted)
constexpr size_t OFF_VSWZ = 20267008;     // vswz [24][13][4][4][64][8] f16
constexpr size_t WS_TOTAL = 25378816;
constexpr int kKoneTot = 13 * 8 * 2 * 64 * 8;   // 106496 f16 elements

__device__ inline f16x4 pack4(float4 v) {
  union { fp16x2_raw h2[2]; f16x4 f4; } u;
  u.h2[0] = __builtin_amdgcn_cvt_pkrtz(v.x, v.y);
  u.h2[1] = __builtin_amdgcn_cvt_pkrtz(v.z, v.w);
  return u.f4;
}

__device__ inline float fast_exp2(float x) {
#if __has_builtin(__builtin_amdgcn_exp2f)
  return __builtin_amdgcn_exp2f(x);
#else
  return __expf(x * 0.6931471805599453f);
#endif
}

// async global -> LDS DMA, 16 bytes per lane (zero VGPR round-trip)
__device__ inline void gload_lds16(const f16* g, f16* l) {
  __builtin_amdgcn_global_load_lds(
      (const __attribute__((address_space(1))) unsigned int*)g,
      (__attribute__((address_space(3))) unsigned int*)l,
      16, 0, 0);
}

// dot of 64-dim q (registers, f16) with 64-dim R row (LDS, f16)
__device__ inline float dotqLDS(const f16x8* qh, const f16* Rrow) {
  float s = 0.f;
#pragma unroll
  for (int i = 0; i < 8; ++i) {
    f16x8 a = qh[i];
    f16x8 b = *(const f16x8*)(Rrow + i * 8);
#pragma unroll
    for (int k = 0; k < 8; ++k) s += (float)a[k] * (float)b[k];
  }
  return s;
}
}

// ---------------- QKV GEMM: 128x128, fp32 in-staging conversion ----------------
// + fused konefrag generation (one element per thread, independent writes;
//   consumed by arp_attn one launch later).
// + XCD-bijective block swizzle (450 = 2x57 + 6x56): blocks sharing an A-panel
//   (same m0) land on one XCD's L2.
__global__ __launch_bounds__(256, 2) void arp_gemm_qkv(
    const float* __restrict__ X, const float* __restrict__ qkvw,
    f16* __restrict__ qf, f16* __restrict__ kfrag, f16* __restrict__ vswz,
    f16* __restrict__ konefrag) {
  __shared__ char smem[34816];
  f16* sA = (f16*)smem;               // [128][40]
  f16* sB = (f16*)(smem + 10240);     // [128][40]
  f16* sE = (f16*)smem;               // [128][136] (epilogue)
  const int tid = threadIdx.x, lane = tid & 63, wv = tid >> 6;

  // ---- fused konefrag generation (key-permuted one-hot ext fragments) ----
  {
    int g = (blockIdx.y * 18 + blockIdx.x) * 256 + tid;
    if (g < kKoneTot) {
      int j = g & 7;
      int ln = (g >> 3) & 63;
      int s2 = (g >> 9) & 1;
      int nt = (g >> 10) & 7;
      int kt = g >> 13;
      int slot = ln & 15, qd = ln >> 4;
      int kin = (nt >> 1) * 32 + (slot >> 2) * 8 + (nt & 1) * 4 + (slot & 3);
      int key = kt * 128 + kin;
      int c = s2 * 32 + qd * 8 + j;
      int t2 = key / kS; int rm = key - t2 * kS;
      int h2 = rm / kWd; int w2 = rm - h2 * kWd;
      if (t2 > kT - 1) t2 = kT - 1;
      float v = 0.f;
      if (c == h2) v = 1.f;
      else if (c == 14 + w2) v = 1.f;
      else if (c == 28 + t2) v = 1.f;
      else if (c == 36 && key >= kN) v = 1.f;
      konefrag[g] = (f16)v;
    }
  }

  // ---- XCD-bijective swizzle: 450 blocks, q=56, r=2 ----
  int orig = blockIdx.y * 18 + blockIdx.x;
  int xcd = orig & 7;
  int base = (xcd < 2) ? xcd * 57 : 2 * 57 + (xcd - 2) * 56;
  int wgid = base + (orig >> 3);
  const int m0 = (wgid / 18) * 128, n0 = (wgid % 18) * 128;

  const int wm = (wv & 1) * 64, wn = (wv >> 1) * 64;
  const int frow = lane & 15, quad = lane >> 4, fcol = quad * 8;
  const f32x4 vzero = {0.f, 0.f, 0.f, 0.f};
  f32x4 acc[4][4];
#pragma unroll
  for (int i = 0; i < 4; ++i)
#pragma unroll
    for (int j = 0; j < 4; ++j) acc[i][j] = vzero;

  float4 pA[2][2], pB[2][2];
#pragma unroll
  for (int i = 0; i < 2; ++i) {
    int idx = i * 256 + tid;
    int r = idx >> 2, c8 = (idx & 3) * 8;
    int gm = m0 + r; if (gm >= kM) gm = kM - 1;
    pA[i][0] = *(const float4*)(X + (size_t)gm * 768 + c8);
    pA[i][1] = *(const float4*)(X + (size_t)gm * 768 + c8 + 4);
    pB[i][0] = *(const float4*)(qkvw + (size_t)(n0 + r) * 768 + c8);
    pB[i][1] = *(const float4*)(qkvw + (size_t)(n0 + r) * 768 + c8 + 4);
  }

  for (int kt = 0; kt < 24; ++kt) {
#pragma unroll
    for (int i = 0; i < 2; ++i) {
      int idx = i * 256 + tid;
      int r = idx >> 2, c8 = (idx & 3) * 8;
      union { f16x4 h[2]; u32x4 u; } ua, ub;
      ua.h[0] = pack4(pA[i][0]); ua.h[1] = pack4(pA[i][1]);
      ub.h[0] = pack4(pB[i][0]); ub.h[1] = pack4(pB[i][1]);
      *(u32x4*)&sA[r * 40 + c8] = ua.u;
      *(u32x4*)&sB[r * 40 + c8] = ub.u;
    }
    __syncthreads();
    if (kt < 23) {
      int ko = (kt + 1) * 32;
#pragma unroll
      for (int i = 0; i < 2; ++i) {
        int idx = i * 256 + tid;
        int r = idx >> 2, c8 = (idx & 3) * 8;
        int gm = m0 + r; if (gm >= kM) gm = kM - 1;
        pA[i][0] = *(const float4*)(X + (size_t)gm * 768 + ko + c8);
        pA[i][1] = *(const float4*)(X + (size_t)gm * 768 + ko + c8 + 4);
        pB[i][0] = *(const float4*)(qkvw + (size_t)(n0 + r) * 768 + ko + c8);
        pB[i][1] = *(const float4*)(qkvw + (size_t)(n0 + r) * 768 + ko + c8 + 4);
      }
    }
    f16x8 af[4], bf[4];
#pragma unroll
    for (int t = 0; t < 4; ++t) {
      af[t] = *(const f16x8*)&sA[(wm + t * 16 + frow) * 40 + fcol];
      bf[t] = *(const f16x8*)&sB[(wn + t * 16 + frow) * 40 + fcol];
    }
#pragma unroll
    for (int mt = 0; mt < 4; ++mt)
#pragma unroll
      for (int nt = 0; nt < 4; ++nt)
        acc[mt][nt] = MFMA16(af[mt], bf[nt], acc[mt][nt]);
    __syncthreads();
  }

  const int which = n0 / 768;   // 0=q, 1=k, 2=v
  if (which == 2) {
#pragma unroll
    for (int mt = 0; mt < 4; ++mt)
#pragma unroll
      for (int nt = 0; nt < 4; ++nt) {
        int cl = wn + nt * 16 + frow;
#pragma unroll
        for (int rg = 0; rg < 4; ++rg) {
          int rl = wm + mt * 16 + quad * 4 + rg;
          sE[cl * 136 + rl] = (f16)acc[mt][nt][rg];
        }
      }
    __syncthreads();
    int cl = tid >> 1;
    int rb = (tid & 1) * 64;
    int rem = n0 + cl - 1536;
    int hh = rem >> 6, d = rem & 63;
    int td = d >> 4, fr = d & 15;
#pragma unroll
    for (int j = 0; j < 8; ++j) {
      int ms = m0 + rb + j * 8;
      if (ms < kM) {
        int bb2 = (ms >= kN) ? 1 : 0;
        int ns = ms - bb2 * kN;
        int bh = bb2 * kHeads + hh;
        int kt2 = ns >> 7, kr = ns & 127;
        int kc = kr >> 5, qd = (kr >> 3) & 3;
        f16* dst = vswz + ((((size_t)(bh * 13 + kt2)) * 4 + td) * 4 + kc) * 512
                        + (qd * 16 + fr) * 8;
        *(u32x4*)dst = *(const u32x4*)&sE[cl * 136 + rb + j * 8];
      }
    }
  } else {
#pragma unroll
    for (int mt = 0; mt < 4; ++mt) {
      int rbase = m0 + wm + mt * 16 + quad * 4;
#pragma unroll
      for (int nt = 0; nt < 4; ++nt) {
        int col0 = n0 + wn + nt * 16;
        int rem = col0 - which * 768;
        int hh = rem >> 6;
        int d = (rem & 63) + frow;
        int s = d >> 5, qd2 = (d >> 3) & 3, j = d & 7;
#pragma unroll
        for (int rg = 0; rg < 4; ++rg) {
          int m = rbase + rg;
          if (m < kM) {
            int bb2 = (m >= kN) ? 1 : 0;
            int ns = m - bb2 * kN;
            int bh = bb2 * kHeads + hh;
            float av = acc[mt][nt][rg];
            if (which == 0) {
              av *= kLog2e;
              qf[((size_t)bh * kNp + ns) * 64 + d] = (f16)av;
            } else {
              av *= 0.125f;
              // key-permuted storage: swapped-QK output becomes PV-ready
              int kt2 = ns >> 7;
              int kin = ns & 127;
              int nt2 = ((kin >> 5) << 1) | ((kin >> 2) & 1);
              int slot = ((kin >> 3) & 3) * 4 + (kin & 3);
              kfrag[(((size_t)(bh * 13 + kt2) * 8 + nt2) * 2 + s) * 512
                    + (qd2 * 16 + slot) * 8 + j] = (f16)av;
            }
          }
        }
      }
    }
  }
}

// ---------------- flash attention; swapped QK^T, P fully in registers ----------
// R4-verified 4-wave structure + XCD-aware work swizzle (R7: FETCH 43.5->8.55MB,
// profiled dur 63->48.5us). Numerics identical to R4. (R12's half-tile dbuf
// variant regressed: same vmcnt-drain volume per key with half the MFMA per
// drain -- full 128-key tiles are optimal for this LDS budget.)
__global__ __launch_bounds__(256, 3) void arp_attn(
    const f16* qf,
    const float* __restrict__ Rh, const float* __restrict__ Rw, const float* __restrict__ Rt,
    const f16* __restrict__ kfrag, const f16* __restrict__ konefrag,
    const f16* __restrict__ vswz, f16* qfO) {
  __shared__ char pool[49152];
  f16* sKa = (f16*)pool;             // 16384 B: K dims 0..63  [nt][s01][64][8]
  f16* sKb = (f16*)(pool + 16384);   // 16384 B: ext dims 64..127
  f16* sV  = (f16*)(pool + 32768);   // 16384 B: V frags [td][kc][64][8]
  f16* sQE = (f16*)pool;             // 8192 B:  [64][64] qe staging (prologue only)
  f16* sR  = (f16*)(pool + 8192);    // 9936 B:  69 rows x 72 f16 (prologue only)

  const int tid = threadIdx.x, lane = tid & 63, wv = tid >> 6;
  // XCD swizzle: L = linear dispatch id (x fastest); XCD = L % 8 (round-robin).
  // L2 = (L%8)*75 + L/8 gives XCD k the contiguous work range [k*75, k*75+75).
  const int Lb  = blockIdx.y * 25 + blockIdx.x;      // 600 blocks
  const int Lw  = (Lb & 7) * 75 + (Lb >> 3);         // bijective (600 = 8*75)
  const int q0 = (Lw % 25) * 64;
  const int bh = Lw / 25;
  const int frow = lane & 15, quad = lane >> 4;
  const f32x4 vzero = {0.f, 0.f, 0.f, 0.f};

  const f16* kba = kfrag + (size_t)bh * 13 * 8192;
  const f16* vba = vswz + (size_t)bh * 13 * 8192;

  // ---- stage R tables: rows 0..26 = Rh, 27..53 = Rw, 54..68 = Rt ----
  for (int g = tid; g < 69 * 16; g += 256) {
    int row = g >> 4, c4 = (g & 15) * 4;
    const float* src = (row < 27) ? Rh + row * 64 + c4
                     : (row < 54) ? Rw + (row - 27) * 64 + c4
                                  : Rt + (row - 54) * 64 + c4;
    *(f16x4*)&sR[row * 72 + c4] = pack4(*(const float4*)src);
  }
  __syncthreads();

  // ---- fused qext, wave-specialized, dots from LDS ----
  {
    int q = q0 + lane;
    int qc = (q < kN) ? q : kN - 1;    // clamp so table indices stay in range
    int tq = qc / kS, sr = qc - tq * kS;
    int hq = sr / kWd, wq = sr - hq * kWd;
    if (wv < 3) {
      f16x8 qh[8];
      const f16x8* qv8 = (const f16x8*)(qf + ((size_t)bh * kNp + q) * 64);
#pragma unroll
      for (int i = 0; i < 8; ++i) qh[i] = qv8[i];
      if (wv == 0) {
#pragma unroll
        for (int e = 0; e < 14; ++e)
          sQE[lane * 64 + e] = (f16)dotqLDS(qh, &sR[(hq - e + 13) * 72]);
      } else if (wv == 1) {
#pragma unroll
        for (int e = 0; e < 14; ++e)
          sQE[lane * 64 + 14 + e] = (f16)dotqLDS(qh, &sR[(wq - e + 40) * 72]);
      } else {
#pragma unroll
        for (int e = 0; e < 8; ++e)
          sQE[lane * 64 + 28 + e] = (f16)dotqLDS(qh, &sR[(tq - e + 61) * 72]);
      }
    } else {
      sQE[lane * 64 + 36] = (f16)(-30000.f);
#pragma unroll
      for (int e = 37; e < 64; ++e) sQE[lane * 64 + e] = (f16)0.f;
    }
  }
  __syncthreads();

  f16x8 aQ0, aQ1, aQE0, aQE1;
  {
    int row = q0 + wv * 16 + frow;
    const f16* qp = qf + ((size_t)bh * kNp + row) * 64;
    aQ0 = *(const f16x8*)(qp + quad * 8);
    aQ1 = *(const f16x8*)(qp + 32 + quad * 8);
    int rl = wv * 16 + frow;
    aQE0 = *(const f16x8*)&sQE[rl * 64 + quad * 8];
    aQE1 = *(const f16x8*)&sQE[rl * 64 + 32 + quad * 8];
  }
  __syncthreads();   // all sQE reads complete before DMA clobbers the pool

  // ---- issue kt=0 staging (async DMA; drained by loop-top barrier) ----
#pragma unroll
  for (int i = 0; i < 4; ++i) {
    int u = (i * 256 + tid) * 8;
    gload_lds16(kba + u, sKa + u);
    gload_lds16(konefrag + u, sKb + u);
    gload_lds16(vba + u, sV + u);
  }

  float den = 0.f;
  f32x4 Oc[4];
#pragma unroll
  for (int t = 0; t < 4; ++t) Oc[t] = vzero;

  for (int kt = 0; kt < 13; ++kt) {
    __syncthreads();  // drains vmcnt: tile resident; all waves aligned

    f32x4 Sc[8];
    __builtin_amdgcn_s_setprio(1);
#pragma unroll
    for (int nt = 0; nt < 8; ++nt) {
      const f16* ka = &sKa[nt * 1024 + lane * 8];
      const f16* kb = &sKb[nt * 1024 + lane * 8];
      f32x4 s = MFMA16(*(const f16x8*)(ka), aQ0, vzero);
      s = MFMA16(*(const f16x8*)(ka + 512), aQ1, s);
      s = MFMA16(*(const f16x8*)(kb), aQE0, s);
      Sc[nt] = MFMA16(*(const f16x8*)(kb + 512), aQE1, s);
    }
    __builtin_amdgcn_s_setprio(0);
    f16x8 bV[4][4];
#pragma unroll
    for (int td = 0; td < 4; ++td)
#pragma unroll
      for (int kc = 0; kc < 4; ++kc)
        bV[td][kc] = *(const f16x8*)&sV[(td * 4 + kc) * 512 + lane * 8];
    __syncthreads();  // all LDS reads done -> safe to DMA next tile

    if (kt < 12) {
      const f16* kfa = kba + (size_t)(kt + 1) * 8192;
      const f16* koa = konefrag + (size_t)(kt + 1) * 8192;
      const f16* vfa = vba + (size_t)(kt + 1) * 8192;
#pragma unroll
      for (int i = 0; i < 4; ++i) {
        int u = (i * 256 + tid) * 8;
        gload_lds16(kfa + u, sKa + u);
        gload_lds16(koa + u, sKb + u);
        gload_lds16(vfa + u, sV + u);
      }
    }

#pragma unroll
    for (int nt = 0; nt < 8; ++nt)
#pragma unroll
      for (int r = 0; r < 4; ++r)
        Sc[nt][r] = fast_exp2(Sc[nt][r]);

    __builtin_amdgcn_s_setprio(1);
#pragma unroll
    for (int kc = 0; kc < 4; ++kc) {
      union { _Float16 h[8]; f16x8 v; } up;
#pragma unroll
      for (int r = 0; r < 4; ++r) {
        up.h[r]     = (f16)Sc[2 * kc][r];
        up.h[4 + r] = (f16)Sc[2 * kc + 1][r];
      }
#pragma unroll
      for (int r = 0; r < 4; ++r)
        den += (float)up.h[r] + (float)up.h[4 + r];
#pragma unroll
      for (int td = 0; td < 4; ++td)
        Oc[td] = MFMA16(up.v, bV[td][kc], Oc[td]);
    }
    __builtin_amdgcn_s_setprio(0);
  }

  // denominator: per-lane partial covers quad-owned keys; reduce across quads
  den += __shfl_xor(den, 16, 64);
  den += __shfl_xor(den, 32, 64);
  float lr[4];
#pragma unroll
  for (int r = 0; r < 4; ++r)
    lr[r] = 1.f / __shfl(den, quad * 4 + r, 64);
#pragma unroll
  for (int td = 0; td < 4; ++td)
#pragma unroll
    for (int r = 0; r < 4; ++r) {
      int row = q0 + wv * 16 + quad * 4 + r;
      if (row < kN) {
        float val = Oc[td][r] * lr[r];
        qfO[((size_t)bh * kNp + row) * 64 + td * 16 + frow] = (f16)val;
      }
    }
}

// ---------------- proj GEMM: 64x64 tiles (grid 588) + XCD-bijective swizzle ----
__global__ __launch_bounds__(256, 4) void arp_gemm_proj(
    const f16* A, const float* __restrict__ projw,
    const float* __restrict__ bias, float* __restrict__ out) {
  __shared__ f16 sA[64 * 40];     // 5120 B
  __shared__ f16 sB[64 * 40];     // 5120 B
  const int tid = threadIdx.x, lane = tid & 63, wv = tid >> 6;

  // XCD-bijective swizzle: 588 blocks, q=73, r=4
  int orig = blockIdx.y * 12 + blockIdx.x;
  int xcd = orig & 7;
  int base = (xcd < 4) ? xcd * 74 : 4 * 74 + (xcd - 4) * 73;
  int wgid = base + (orig >> 3);
  const int m0 = (wgid / 12) * 64, n0 = (wgid % 12) * 64;

  const int frow = lane & 15, quad = lane >> 4, fcol = quad * 8;
  const f32x4 vzero = {0.f, 0.f, 0.f, 0.f};
  f32x4 acc[4];
#pragma unroll
  for (int j = 0; j < 4; ++j) acc[j] = vzero;

  u32x4 pA;
  float4 pB[2];
  {
    int r = tid >> 2, c8 = (tid & 3) * 8;
    int m = m0 + r;
    int bb = (m >= kN) ? 1 : 0;
    int ns = m - bb * kN;
    pA = *(const u32x4*)(A + ((size_t)(bb * kHeads) * kNp + ns) * 64 + c8);
    pB[0] = *(const float4*)(projw + (size_t)(n0 + r) * 768 + c8);
    pB[1] = *(const float4*)(projw + (size_t)(n0 + r) * 768 + c8 + 4);
  }

  for (int kt = 0; kt < 24; ++kt) {
    {
      int r = tid >> 2, c8 = (tid & 3) * 8;
      *(u32x4*)&sA[r * 40 + c8] = pA;
      union { f16x4 h[2]; u32x4 u; } ub;
      ub.h[0] = pack4(pB[0]); ub.h[1] = pack4(pB[1]);
      *(u32x4*)&sB[r * 40 + c8] = ub.u;
    }
    __syncthreads();
    if (kt < 23) {
      int k1 = kt + 1;
      int hd = k1 >> 1, dof = (k1 & 1) * 32;
      int r = tid >> 2, c8 = (tid & 3) * 8;
      int m = m0 + r;
      int bb = (m >= kN) ? 1 : 0;
      int ns = m - bb * kN;
      pA = *(const u32x4*)(A + ((size_t)(bb * kHeads + hd) * kNp + ns) * 64 + dof + c8);
      pB[0] = *(const float4*)(projw + (size_t)(n0 + r) * 768 + k1 * 32 + c8);
      pB[1] = *(const float4*)(projw + (size_t)(n0 + r) * 768 + k1 * 32 + c8 + 4);
    }
    f16x8 af = *(const f16x8*)&sA[(wv * 16 + frow) * 40 + fcol];
    f16x8 bf[4];
#pragma unroll
    for (int u = 0; u < 4; ++u)
      bf[u] = *(const f16x8*)&sB[(u * 16 + frow) * 40 + fcol];
#pragma unroll
    for (int u = 0; u < 4; ++u)
      acc[u] = MFMA16(af, bf[u], acc[u]);
    __syncthreads();
  }
#pragma unroll
  for (int u = 0; u < 4; ++u) {
    int col = n0 + u * 16 + frow;
    float bv = bias[col];
#pragma unroll
    for (int rg = 0; rg < 4; ++rg) {
      int m = m0 + wv * 16 + quad * 4 + rg;
      out[(size_t)m * 768 + col] = acc[u][rg] + bv;
    }
  }
}

extern "C" void kernel_launch(void* const* d_in, const int* in_sizes, int n_in,
                              void* d_out, int out_size, void* d_ws, size_t ws_size,
                              hipStream_t stream) {
  if (ws_size < WS_TOTAL) return;
  const float* x      = (const float*)d_in[0];
  const float* qkv_w  = (const float*)d_in[1];
  const float* proj_w = (const float*)d_in[2];
  const float* proj_b = (const float*)d_in[3];
  const float* rph    = (const float*)d_in[4];
  const float* rpw    = (const float*)d_in[5];
  const float* rpt    = (const float*)d_in[6];
  char* ws = (char*)d_ws;
  f16* qf       = (f16*)(ws + OFF_Q);     // becomes O after attn (in-place)
  f16* kfrag    = (f16*)(ws + OFF_KF);
  f16* konefrag = (f16*)(ws + OFF_KONE);
  f16* vswz     = (f16*)(ws + OFF_VSWZ);

  arp_gemm_qkv<<<dim3(18, 25), 256, 0, stream>>>(x, qkv_w, qf, kfrag, vswz, konefrag);
  arp_attn<<<dim3(25, 24), 256, 0, stream>>>(qf, rph, rpw, rpt, kfrag, konefrag, vswz, qf);
  arp_gemm_proj<<<dim3(12, 49), 256, 0, stream>>>(qf, proj_w, proj_b, (float*)d_out);
}